// Round 1
// baseline (526.378 us; speedup 1.0000x reference)
//
#include <hip/hip_runtime.h>
#include <math.h>

#define Bb 8
#define Ss 2048
#define Ee 256
#define Hh 4
#define Dd 64

typedef unsigned short u16;
typedef unsigned int u32;
typedef __attribute__((ext_vector_type(8))) short bf16x8;
typedef __attribute__((ext_vector_type(4))) float f32x4;
typedef __attribute__((ext_vector_type(16))) float f32x16;

__device__ __forceinline__ u16 f2bf(float f) {
  union { float f; u32 u; } c; c.f = f;
  return (u16)((c.u + 0x7FFFu + ((c.u >> 16) & 1u)) >> 16);
}
__device__ __forceinline__ float bf2f(u16 u) {
  union { u32 u; float f; } c; c.u = ((u32)u) << 16;
  return c.f;
}
__device__ __forceinline__ float bf2fs(short s) { return bf2f((u16)s); }
__device__ __forceinline__ u32 cvtpk(float a, float b) {
  u32 r;
  asm("v_cvt_pk_bf16_f32 %0, %1, %2" : "=v"(r) : "v"(a), "v"(b));
  return r;
}
__device__ __forceinline__ float ex2(float x) { return __builtin_amdgcn_exp2f(x); }

// ---------------- weight fp32 -> bf16 convert ----------------
__global__ __launch_bounds__(256) void k_w2b(const float* __restrict__ src,
                                             u16* __restrict__ dst) {
  int idx = (blockIdx.x * 256 + threadIdx.x) * 4;
  float4 v = *reinterpret_cast<const float4*>(src + idx);
  ushort4 o;
  o.x = f2bf(v.x); o.y = f2bf(v.y); o.z = f2bf(v.z); o.w = f2bf(v.w);
  *reinterpret_cast<ushort4*>(dst + idx) = o;
}

// ---------------- embedding gather (fp32 x + bf16 xb) ----------------
__global__ __launch_bounds__(256) void k_gather(const int* __restrict__ seqs,
                                                const float* __restrict__ emb,
                                                float* __restrict__ x,
                                                u16* __restrict__ xb) {
  int idx = blockIdx.x * 256 + threadIdx.x;
  int row = idx >> 6, c4 = idx & 63;
  int tok = seqs[row];
  float4 v = reinterpret_cast<const float4*>(emb)[(size_t)tok * 64 + c4];
  reinterpret_cast<float4*>(x)[(size_t)row * 64 + c4] = v;
  ushort4 o;
  o.x = f2bf(v.x); o.y = f2bf(v.y); o.z = f2bf(v.z); o.w = f2bf(v.w);
  reinterpret_cast<ushort4*>(xb)[(size_t)row * 64 + c4] = o;
}

// ---------------- QKV projection (MFMA bf16): relu(xb@W^T+b) -> bf16 --------
// Q output pre-scaled by log2(e)/16 (folds attention scale AND exp->exp2).
__global__ __launch_bounds__(256) void k_qkvm(const u16* __restrict__ xb,
    const u16* __restrict__ Wqb, const u16* __restrict__ Wkb, const u16* __restrict__ Wvb,
    const float* __restrict__ bq, const float* __restrict__ bk, const float* __restrict__ bv,
    u16* __restrict__ Qf, u16* __restrict__ Kf, u16* __restrict__ Vf, int mod) {
  __shared__ short Xs[128][72];
  __shared__ short Ws[128][72];
  int tid = threadIdx.x;
  int bn = blockIdx.x;
  int arr = bn >> 1, coff = (bn & 1) << 7;
  const u16* W = (arr == 0 ? Wqb : arr == 1 ? Wkb : Wvb) + (size_t)mod * 256 * 256;
  const float* bias = (arr == 0 ? bq : arr == 1 ? bk : bv) + mod * 256;
  u16* Out = (arr == 0 ? Qf : arr == 1 ? Kf : Vf);
  float oscale = (arr == 0) ? 0.0625f * 1.44269504f : 1.0f;
  int s0 = blockIdx.y * 128;
  int lr = tid >> 1, lc = (tid & 1) << 5;
  int w = tid >> 6, lane = tid & 63, ml = lane & 15, q = lane >> 4;
  int sh = (w >> 1) << 6, th = (w & 1) << 6;
  f32x4 acc[4][4] = {};
  for (int k0 = 0; k0 < 256; k0 += 64) {
#pragma unroll
    for (int hh = 0; hh < 4; hh++) {
      *reinterpret_cast<bf16x8*>(&Xs[lr][lc + hh * 8]) =
          *reinterpret_cast<const bf16x8*>(xb + (size_t)(s0 + lr) * Ee + k0 + lc + hh * 8);
      *reinterpret_cast<bf16x8*>(&Ws[lr][lc + hh * 8]) =
          *reinterpret_cast<const bf16x8*>(W + (size_t)(coff + lr) * Ee + k0 + lc + hh * 8);
    }
    __syncthreads();
#pragma unroll
    for (int ks = 0; ks < 2; ks++) {
      bf16x8 af[4], bfr[4];
#pragma unroll
      for (int mt = 0; mt < 4; mt++)
        af[mt] = *reinterpret_cast<const bf16x8*>(&Xs[sh + mt * 16 + ml][ks * 32 + q * 8]);
#pragma unroll
      for (int nt = 0; nt < 4; nt++)
        bfr[nt] = *reinterpret_cast<const bf16x8*>(&Ws[th + nt * 16 + ml][ks * 32 + q * 8]);
#pragma unroll
      for (int mt = 0; mt < 4; mt++)
#pragma unroll
        for (int nt = 0; nt < 4; nt++)
          acc[mt][nt] = __builtin_amdgcn_mfma_f32_16x16x32_bf16(af[mt], bfr[nt], acc[mt][nt], 0, 0, 0);
    }
    __syncthreads();
  }
#pragma unroll
  for (int mt = 0; mt < 4; mt++)
#pragma unroll
    for (int nt = 0; nt < 4; nt++)
#pragma unroll
      for (int r = 0; r < 4; r++) {
        int gm = s0 + sh + mt * 16 + q * 4 + r;
        int cc = coff + th + nt * 16 + ml;
        float v = acc[mt][nt][r] + bias[cc];
        v = (v > 0.f ? v : 0.f) * oscale;
        Out[(size_t)gm * Ee + cc] = f2bf(v);
      }
}

// ---------------- V transpose: Vf[b][t][h*64+d] -> Vt[(b*4+h)*64+d][t] -------
__global__ __launch_bounds__(256) void k_vt(const u16* __restrict__ Vf,
                                            u16* __restrict__ Vt) {
  __shared__ u16 T[64][72];
  int tid = threadIdx.x;
  int t0 = blockIdx.x * 64;
  int z = blockIdx.y;
  int b = z >> 2, h = z & 3;
  int lr = tid >> 2, lc = (tid & 3) << 4;
#pragma unroll
  for (int hh = 0; hh < 2; hh++) {
    bf16x8 v = *reinterpret_cast<const bf16x8*>(
        Vf + (size_t)(b * Ss + t0 + lr) * Ee + h * Dd + lc + hh * 8);
#pragma unroll
    for (int j = 0; j < 8; j++) T[lr][lc + hh * 8 + j] = (u16)v[j];
  }
  __syncthreads();
#pragma unroll
  for (int j = 0; j < 16; j++) {
    Vt[((size_t)z * Dd + lr) * Ss + t0 + lc + j] = T[lc + j][lr];
  }
}

// ---------------- SV[z][d] = sum_t Vt[z*64+d][t]; also zero csums ------------
__global__ __launch_bounds__(256) void k_vsum(const u16* __restrict__ Vt,
                                              float* __restrict__ SV,
                                              float* __restrict__ csums) {
  int gi = (blockIdx.y * gridDim.x + blockIdx.x) * 256 + threadIdx.x;
  if (gi < 32 * Ss) csums[gi] = 0.f;
  int z = blockIdx.y;
  int d = blockIdx.x * 4 + (threadIdx.x >> 6);
  int lane = threadIdx.x & 63;
  const u16* row = Vt + ((size_t)z * Dd + d) * Ss;
  float s = 0.f;
#pragma unroll
  for (int it = 0; it < 4; it++) {
    bf16x8 v = *reinterpret_cast<const bf16x8*>(row + it * 512 + lane * 8);
#pragma unroll
    for (int j = 0; j < 8; j++) s += bf2fs(v[j]);
  }
#pragma unroll
  for (int off = 32; off; off >>= 1) s += __shfl_xor(s, off);
  if (lane == 0) SV[(size_t)z * Dd + d] = s;
}

// ---------------- pass 1: csums[t] += sum_s exp2(S) (barrier-free loop) ------
// grid (16 t-tiles, 2 s-halves, 32 z). K frags + Q frags straight from global.
// S is already in log2 units (Q pre-scaled by log2e/16).
__global__ __launch_bounds__(256, 4) void k_csum(const u16* __restrict__ Qf,
    const u16* __restrict__ Kf, float* __restrict__ csums) {
  __shared__ float csm[2][128];
  int tid = threadIdx.x;
  int lin = (blockIdx.z * 2 + blockIdx.y) * 16 + blockIdx.x;
  int wgid = (lin & 7) * 128 + (lin >> 3);   // XCD-chunked, bijective (1024 % 8 == 0)
  int ttile = wgid & 15, shalf = (wgid >> 4) & 1, z = wgid >> 5;
  int b = z >> 2, h = z & 3;
  const u16* Qb = Qf + (size_t)b * Ss * Ee + h * Dd;
  const u16* Kb = Kf + (size_t)b * Ss * Ee + h * Dd;
  int w = tid >> 6, lane = tid & 63, l31 = lane & 31, hi = lane >> 5;
  int sh = (w >> 1) << 6, th = (w & 1) << 6;
  const u16* kr = Kb + (size_t)(ttile * 128 + th + l31) * Ee + hi * 8;
  bf16x8 kb[2][4];
#pragma unroll
  for (int tt = 0; tt < 2; tt++)
#pragma unroll
    for (int kk = 0; kk < 4; kk++)
      kb[tt][kk] = *reinterpret_cast<const bf16x8*>(kr + (size_t)tt * 32 * Ee + kk * 16);
  float cs0 = 0.f, cs1 = 0.f;
  int sBeg = shalf * 1024, sEnd = sBeg + 1024;
  for (int s0 = sBeg; s0 < sEnd; s0 += 128) {
#pragma unroll
    for (int qs = 0; qs < 2; qs++) {
      const u16* Qr = Qb + (size_t)(s0 + sh + qs * 32 + l31) * Ee + hi * 8;
      f32x16 a0 = {}, a1 = {};
      __builtin_amdgcn_s_setprio(1);
#pragma unroll
      for (int kk = 0; kk < 4; kk++) {
        bf16x8 qv = *reinterpret_cast<const bf16x8*>(Qr + kk * 16);
        a0 = __builtin_amdgcn_mfma_f32_32x32x16_bf16(qv, kb[0][kk], a0, 0, 0, 0);
        a1 = __builtin_amdgcn_mfma_f32_32x32x16_bf16(qv, kb[1][kk], a1, 0, 0, 0);
      }
      __builtin_amdgcn_s_setprio(0);
#pragma unroll
      for (int j = 0; j < 16; j++) { cs0 += ex2(a0[j]); cs1 += ex2(a1[j]); }
    }
  }
  cs0 += __shfl_xor(cs0, 32);
  cs1 += __shfl_xor(cs1, 32);
  if (lane < 32) {
    csm[w >> 1][th + l31] = cs0;
    csm[w >> 1][th + 32 + l31] = cs1;
  }
  __syncthreads();
  if (tid < 128)
    atomicAdd(&csums[(size_t)z * Ss + ttile * 128 + tid], csm[0][tid] + csm[1][tid]);
}

// ---------------- csums -> llic = -log2(csums), in place ---------------------
__global__ void k_llog(float* __restrict__ llic) {
  int i = blockIdx.x * 256 + threadIdx.x;
  llic[i] = -__log2f(llic[i]);
}

// ---------------- pass 2: fused attention (transposed QK, 32x32 MFMA) --------
// grid (32 s-tiles of 64 rows, 32 z). Per 64-t chunk:
//   QK^T as mfma(K,Q) -> C[t,s] (t on reg axis) -> e1=exp2(S+llic) ->
//   A2'=expm1-poly -> cvt_pk pairs -> b64 stores to A2s[s][t] -> PV-MFMA.
// K frags from global regs (prefetched); V double-buffered in LDS.
// O = (SV + A2'@V) / (2048 + rowsum(A2')) -> bf16 Zb.
__global__ __launch_bounds__(256, 4) void k_att(const u16* __restrict__ Qf,
    const u16* __restrict__ Kf, const u16* __restrict__ Vt,
    const float* __restrict__ llic, const float* __restrict__ SV,
    u16* __restrict__ Zb) {
  __shared__ short Vs[2][64 * 72];
  __shared__ short A2s[64 * 72];
  __shared__ float rs_s[2][64];
  int tid = threadIdx.x;
  int lin = blockIdx.y * 32 + blockIdx.x;
  int wgid = (lin & 7) * 128 + (lin >> 3);   // XCD-chunked, bijective
  int z = wgid >> 5, sblk = wgid & 31;
  int b = z >> 2, h = z & 3;
  const u16* Qb = Qf + (size_t)b * Ss * Ee + h * Dd;
  const u16* Kb = Kf + (size_t)b * Ss * Ee + h * Dd;
  const u16* VtZ = Vt + (size_t)z * Dd * Ss;
  const float* lz = llic + (size_t)z * Ss;
  int s0 = sblk * 64;
  int w = tid >> 6, lane = tid & 63;
  int l31 = lane & 31, hi = lane >> 5;
  int tw = w >> 1, sw = w & 1;
  // Q B-frags (loop-invariant): rows s0+sw*32+l31, k = kk*16 + hi*8
  const u16* qrow = Qb + (size_t)(s0 + sw * 32 + l31) * Ee + hi * 8;
  bf16x8 qb0 = *reinterpret_cast<const bf16x8*>(qrow);
  bf16x8 qb1 = *reinterpret_cast<const bf16x8*>(qrow + 16);
  bf16x8 qb2 = *reinterpret_cast<const bf16x8*>(qrow + 32);
  bf16x8 qb3 = *reinterpret_cast<const bf16x8*>(qrow + 48);
  // K frag base (advance by t*Ee per chunk)
  const u16* krow = Kb + (size_t)(tw * 32 + l31) * Ee + hi * 8;
  bf16x8 kf0 = *reinterpret_cast<const bf16x8*>(krow);
  bf16x8 kf1 = *reinterpret_cast<const bf16x8*>(krow + 16);
  bf16x8 kf2 = *reinterpret_cast<const bf16x8*>(krow + 32);
  bf16x8 kf3 = *reinterpret_cast<const bf16x8*>(krow + 48);
  // stage V chunk 0
  int sd = tid >> 2, sg = (tid & 3) << 4;
  {
    const u16* vsrc = VtZ + (size_t)sd * Ss + sg;
    *reinterpret_cast<bf16x8*>(&Vs[0][sd * 72 + sg]) = *reinterpret_cast<const bf16x8*>(vsrc);
    *reinterpret_cast<bf16x8*>(&Vs[0][sd * 72 + sg + 8]) = *reinterpret_cast<const bf16x8*>(vsrc + 8);
  }
  f32x16 acc2 = {};
  float rsv = 0.f;
  int pb = 0;
  short* arow = &A2s[(sw * 32 + l31) * 72 + tw * 32];
  const short* a2row = &A2s[(tw * 32 + l31) * 72 + hi * 8];
  for (int t0 = 0; t0 < Ss; t0 += 64) {
    // QK: C[t = tw*32 + reg-axis][s = sw*32 + l31]
    f32x16 at = {};
    __builtin_amdgcn_s_setprio(1);
    at = __builtin_amdgcn_mfma_f32_32x32x16_bf16(kf0, qb0, at, 0, 0, 0);
    at = __builtin_amdgcn_mfma_f32_32x32x16_bf16(kf1, qb1, at, 0, 0, 0);
    at = __builtin_amdgcn_mfma_f32_32x32x16_bf16(kf2, qb2, at, 0, 0, 0);
    at = __builtin_amdgcn_mfma_f32_32x32x16_bf16(kf3, qb3, at, 0, 0, 0);
    __builtin_amdgcn_s_setprio(0);
    // prefetch next chunk's K frags
    int tn = (t0 + 64 < Ss) ? t0 + 64 : 0;
    {
      const u16* krn = krow + (size_t)tn * Ee;
      kf0 = *reinterpret_cast<const bf16x8*>(krn);
      kf1 = *reinterpret_cast<const bf16x8*>(krn + 16);
      kf2 = *reinterpret_cast<const bf16x8*>(krn + 32);
      kf3 = *reinterpret_cast<const bf16x8*>(krn + 48);
    }
    // transform: e1 = exp2(S*log2e + llic); A2' = expm1(e1) poly4
#pragma unroll
    for (int g = 0; g < 4; g++) {
      const float4 lc = *reinterpret_cast<const float4*>(lz + t0 + tw * 32 + g * 8 + hi * 4);
      float e0 = ex2(at[g * 4 + 0] + lc.x);
      float e1 = ex2(at[g * 4 + 1] + lc.y);
      float e2 = ex2(at[g * 4 + 2] + lc.z);
      float e3 = ex2(at[g * 4 + 3] + lc.w);
      float p0 = e0 * (1.f + e0 * (0.5f + e0 * (0.166666667f + e0 * 0.0416666667f)));
      float p1 = e1 * (1.f + e1 * (0.5f + e1 * (0.166666667f + e1 * 0.0416666667f)));
      float p2 = e2 * (1.f + e2 * (0.5f + e2 * (0.166666667f + e2 * 0.0416666667f)));
      float p3 = e3 * (1.f + e3 * (0.5f + e3 * (0.166666667f + e3 * 0.0416666667f)));
      rsv += (p0 + p1) + (p2 + p3);
      uint2 pk;
      pk.x = cvtpk(p0, p1);
      pk.y = cvtpk(p2, p3);
      *reinterpret_cast<uint2*>(arow + g * 8 + hi * 4) = pk;
    }
    __syncthreads();
    // stage next V into other buffer (overlaps PV)
    {
      const u16* vsrc = VtZ + (size_t)sd * Ss + tn + sg;
      bf16x8 v0 = *reinterpret_cast<const bf16x8*>(vsrc);
      bf16x8 v1 = *reinterpret_cast<const bf16x8*>(vsrc + 8);
      short* vdst = &Vs[pb ^ 1][sd * 72 + sg];
      *reinterpret_cast<bf16x8*>(vdst) = v0;
      *reinterpret_cast<bf16x8*>(vdst + 8) = v1;
    }
    // PV: wave (tw,sw) -> C[s = tw*32 + reg-axis][d = sw*32 + l31]
    {
      const short* vrow = &Vs[pb][(sw * 32 + l31) * 72 + hi * 8];
      __builtin_amdgcn_s_setprio(1);
#pragma unroll
      for (int kk = 0; kk < 4; kk++) {
        bf16x8 af2 = *reinterpret_cast<const bf16x8*>(a2row + kk * 16);
        bf16x8 bvv = *reinterpret_cast<const bf16x8*>(vrow + kk * 16);
        acc2 = __builtin_amdgcn_mfma_f32_32x32x16_bf16(af2, bvv, acc2, 0, 0, 0);
      }
      __builtin_amdgcn_s_setprio(0);
    }
    __syncthreads();
    pb ^= 1;
  }
  // rowsum: lane's rsv covers its (hi, tw) share; combine hi via shfl, tw via LDS
  rsv += __shfl_xor(rsv, 32);
  if (lane < 32) rs_s[tw][sw * 32 + l31] = rsv;
  __syncthreads();
  float svd = SV[(size_t)z * Dd + sw * 32 + l31];
#pragma unroll
  for (int g = 0; g < 4; g++)
#pragma unroll
    for (int rr = 0; rr < 4; rr++) {
      int row = tw * 32 + g * 8 + hi * 4 + rr;
      float inv = 1.f / (2048.f + rs_s[0][row] + rs_s[1][row]);
      float o = (svd + acc2[g * 4 + rr]) * inv;
      Zb[(size_t)(b * Ss + s0 + row) * Ee + h * Dd + sw * 32 + l31] = f2bf(o);
    }
}

// ---------------- ZF (MFMA bf16) + residual: x += Zb@Wz^T + bz; xb refresh ---
__global__ __launch_bounds__(256) void k_zfm(const u16* __restrict__ Zb,
    const u16* __restrict__ Wzb, const float* __restrict__ bzp,
    float* __restrict__ x, u16* __restrict__ xb, int mod) {
  __shared__ short Zs[128][72];
  __shared__ short Ws[128][72];
  int tid = threadIdx.x;
  int coff = blockIdx.x << 7;
  const u16* W = Wzb + (size_t)mod * 256 * 256;
  const float* bias = bzp + mod * Ee;
  int s0 = blockIdx.y * 128;
  int lr = tid >> 1, lc = (tid & 1) << 5;
  int w = tid >> 6, lane = tid & 63, ml = lane & 15, q = lane >> 4;
  int sh = (w >> 1) << 6, th = (w & 1) << 6;
  f32x4 acc[4][4] = {};
  for (int k0 = 0; k0 < 256; k0 += 64) {
#pragma unroll
    for (int hh = 0; hh < 4; hh++) {
      *reinterpret_cast<bf16x8*>(&Zs[lr][lc + hh * 8]) =
          *reinterpret_cast<const bf16x8*>(Zb + (size_t)(s0 + lr) * Ee + k0 + lc + hh * 8);
      *reinterpret_cast<bf16x8*>(&Ws[lr][lc + hh * 8]) =
          *reinterpret_cast<const bf16x8*>(W + (size_t)(coff + lr) * Ee + k0 + lc + hh * 8);
    }
    __syncthreads();
#pragma unroll
    for (int ks = 0; ks < 2; ks++) {
      bf16x8 af[4], bfr[4];
#pragma unroll
      for (int mt = 0; mt < 4; mt++)
        af[mt] = *reinterpret_cast<const bf16x8*>(&Zs[sh + mt * 16 + ml][ks * 32 + q * 8]);
#pragma unroll
      for (int nt = 0; nt < 4; nt++)
        bfr[nt] = *reinterpret_cast<const bf16x8*>(&Ws[th + nt * 16 + ml][ks * 32 + q * 8]);
#pragma unroll
      for (int mt = 0; mt < 4; mt++)
#pragma unroll
        for (int nt = 0; nt < 4; nt++)
          acc[mt][nt] = __builtin_amdgcn_mfma_f32_16x16x32_bf16(af[mt], bfr[nt], acc[mt][nt], 0, 0, 0);
    }
    __syncthreads();
  }
#pragma unroll
  for (int mt = 0; mt < 4; mt++)
#pragma unroll
    for (int nt = 0; nt < 4; nt++)
#pragma unroll
      for (int r = 0; r < 4; r++) {
        int gm = s0 + sh + mt * 16 + q * 4 + r;
        int gn = coff + th + nt * 16 + ml;
        float xv = x[(size_t)gm * Ee + gn] + acc[mt][nt][r] + bias[gn];
        x[(size_t)gm * Ee + gn] = xv;
        xb[(size_t)gm * Ee + gn] = f2bf(xv);
      }
}

// ---------------- final head ----------------
__global__ __launch_bounds__(256) void k_final1(const float* __restrict__ x,
    const float* __restrict__ Wo, float* __restrict__ part) {
  int c = blockIdx.x, l = blockIdx.y, b = blockIdx.z;
  int tid = threadIdx.x;
  const float4* xr = reinterpret_cast<const float4*>(x + (size_t)b * (Ss * Ee) + c * 8192);
  const float4* wr = reinterpret_cast<const float4*>(Wo + (size_t)l * (Ss * Ee) + c * 8192);
  float sum = 0.f;
  for (int i = tid; i < 2048; i += 256) {
    float4 a = xr[i], w = wr[i];
    sum += a.x * w.x + a.y * w.y + a.z * w.z + a.w * w.w;
  }
  __shared__ float red[256];
  red[tid] = sum;
  __syncthreads();
  for (int o = 128; o; o >>= 1) {
    if (tid < o) red[tid] += red[tid + o];
    __syncthreads();
  }
  if (tid == 0) part[((b * 16 + l) << 6) + c] = red[0];
}

__global__ void k_final2(const float* __restrict__ part, const float* __restrict__ bo,
                         float* __restrict__ out) {
  int idx = threadIdx.x;   // 128 = 8*16
  int b = idx >> 4, l = idx & 15;
  float s = 0.f;
  for (int c = 0; c < 64; c++) s += part[((b * 16 + l) << 6) + c];
  s += bo[l];
  out[idx] = 1.f / (1.f + __expf(-s));
}

extern "C" void kernel_launch(void* const* d_in, const int* in_sizes, int n_in,
                              void* d_out, int out_size, void* d_ws, size_t ws_size,
                              hipStream_t stream) {
  const int*   seqs = (const int*)d_in[0];
  const float* emb  = (const float*)d_in[1];
  const float* Wq   = (const float*)d_in[2];
  const float* bq   = (const float*)d_in[3];
  const float* Wk   = (const float*)d_in[4];
  const float* bk   = (const float*)d_in[5];
  const float* Wv   = (const float*)d_in[6];
  const float* bv   = (const float*)d_in[7];
  const float* Wz   = (const float*)d_in[8];
  const float* bz   = (const float*)d_in[9];
  const float* Wo   = (const float*)d_in[10];
  const float* bo   = (const float*)d_in[11];
  float* out = (float*)d_out;
  float* ws  = (float*)d_ws;

  float* x    = ws;                                    // 4,194,304 f
  u16*   xb   = (u16*)(ws + 4194304);
  u16*   Qf   = (u16*)(ws + 6291456);
  u16*   Kf   = (u16*)(ws + 8388608);
  u16*   Vf   = (u16*)(ws + 10485760);
  u16*   Vt   = (u16*)(ws + 12582912);
  u16*   Zb   = (u16*)(ws + 14680064);
  float* SV   = ws + 16777216;                         // 2,048 f
  float* part = ws + 16779264;                         // 8,192 f
  u16*   Wqb  = (u16*)(ws + 16787456);
  u16*   Wkb  = (u16*)(ws + 16852992);
  u16*   Wvb  = (u16*)(ws + 16918528);
  u16*   Wzb  = (u16*)(ws + 16984064);
  float* llic = ws + 17049600;                         // 65,536 f (csums then -log2)

  k_gather<<<(Bb * Ss * 64) / 256, 256, 0, stream>>>(seqs, emb, x, xb);
  k_w2b<<<131072 / 1024, 256, 0, stream>>>(Wq, Wqb);
  k_w2b<<<131072 / 1024, 256, 0, stream>>>(Wk, Wkb);
  k_w2b<<<131072 / 1024, 256, 0, stream>>>(Wv, Wvb);
  k_w2b<<<131072 / 1024, 256, 0, stream>>>(Wz, Wzb);

  for (int m = 0; m < 2; m++) {
    k_qkvm<<<dim3(6, 128), 256, 0, stream>>>(xb, Wqb, Wkb, Wvb, bq, bk, bv, Qf, Kf, Vf, m);
    k_vt<<<dim3(32, 32), 256, 0, stream>>>(Vf, Vt);
    k_vsum<<<dim3(16, 32), 256, 0, stream>>>(Vt, SV, llic);
    k_csum<<<dim3(16, 2, 32), 256, 0, stream>>>(Qf, Kf, llic);
    k_llog<<<256, 256, 0, stream>>>(llic);
    k_att<<<dim3(32, 32), 256, 0, stream>>>(Qf, Kf, Vt, llic, SV, Zb);
    k_zfm<<<dim3(2, 128), 256, 0, stream>>>(Zb, Wzb, bz, x, xb, m);
  }

  k_final1<<<dim3(64, 16, 8), 256, 0, stream>>>(x, Wo, part);
  k_final2<<<1, 128, 0, stream>>>(part, bo, out);
}